// Round 1
// baseline (662.803 us; speedup 1.0000x reference)
//
#include <hip/hip_runtime.h>
#include <math.h>

#define NCH   32
#define NCLS  8
#define NPIX  (8 * 256 * 256)          // B*H*W pixels
#define TRI   528                      // 32*33/2 packed lower-triangular

// Per-launch precomputed constants (rewritten every kernel_launch; no ws needed).
__device__ float g_tri[NCLS * TRI];    // packed rows of Linv_k (lower tri)
__device__ float g_offn[NCLS * NCH];   // -(Linv_k @ mean_k)
__device__ float g_lc2[NCLS];          // (-16*ln(2pi) - logdet_k) * log2(e)

// ---------------------------------------------------------------------------
// Setup: invert the 8 lower-triangular 32x32 factors (fp64 forward
// substitution, one thread per (class, column)), fold mean and log-det.
// ---------------------------------------------------------------------------
__global__ __launch_bounds__(256) void setup_kernel(const float* __restrict__ mean,
                                                    const float* __restrict__ scale) {
  __shared__ float sinv[NCLS][NCH][NCH];
  const int t = threadIdx.x;
  const int k = t >> 5;                // class
  const int j = t & 31;                // column of Linv
  const float* L = scale + k * NCH * NCH;

  double y[NCH];
  #pragma unroll
  for (int i = 0; i < NCH; ++i) {
    double s = (i == j) ? 1.0 : 0.0;
    #pragma unroll
    for (int m = 0; m < i; ++m) s -= (double)L[i * NCH + m] * y[m];
    y[i] = (i < j) ? 0.0 : (s / (double)L[i * NCH + i]);
  }
  #pragma unroll
  for (int i = 0; i < NCH; ++i) sinv[k][i][j] = (float)y[i];
  __syncthreads();

  // thread (k, j) now handles row j of class k
  {
    const int base = k * TRI + j * (j + 1) / 2;
    for (int m = 0; m <= j; ++m) g_tri[base + m] = sinv[k][j][m];
  }
  {
    double o = 0.0;
    for (int m = 0; m <= j; ++m) o += (double)sinv[k][j][m] * (double)mean[k * NCH + m];
    g_offn[k * NCH + j] = (float)(-o);
  }
  if (j == 0) {
    double ld = 0.0;
    for (int i = 0; i < NCH; ++i) ld += log(fabs((double)L[i * NCH + i]));
    const double LOG_2PI = 1.8378770664093454836;
    const double LOG2E   = 1.4426950408889634074;
    g_lc2[k] = (float)((-0.5 * NCH * LOG_2PI - ld) * LOG2E);
  }
}

// ---------------------------------------------------------------------------
// Main: one thread = one pixel for compute; LDS transpose for the coalesced
// 256-floats-per-pixel epilogue. xs float4 slots are XOR-swizzled by pixel to
// avoid the 128B-row-stride bank pathology.
// ---------------------------------------------------------------------------
__global__ __launch_bounds__(256, 3) void fuzzy_main(const float* __restrict__ x,
                                                     float* __restrict__ out) {
  __shared__ float xs[256 * NCH];      // 32 KB, swizzled float4 slots
  __shared__ float gs[256 * 9];        // prob[8] + inv per pixel, stride 9 (9 KB)
  const int t = threadIdx.x;
  const long long pixBase = (long long)blockIdx.x * 256;

  // Phase A: fully coalesced global -> LDS stage of the block's 256 pixel rows
  {
    const float4* gx = reinterpret_cast<const float4*>(x + pixBase * NCH);
    #pragma unroll
    for (int i = 0; i < 8; ++i) {
      const float4 v = gx[i * 256 + t];
      const int p = i * 32 + (t >> 3); // pixel-in-block this float4 belongs to
      const int c = t & 7;             // chunk index within the pixel row
      reinterpret_cast<float4*>(xs)[p * 8 + (c ^ (p & 7))] = v;
    }
  }
  __syncthreads();

  // Phase B: own row -> registers (swizzle-aware, conflict-spread b128 reads)
  float xv[NCH];
  {
    const float4* row = reinterpret_cast<const float4*>(xs + t * NCH);
    #pragma unroll
    for (int i = 0; i < 8; ++i) {
      const float4 v = row[i ^ (t & 7)];
      xv[4 * i + 0] = v.x; xv[4 * i + 1] = v.y;
      xv[4 * i + 2] = v.z; xv[4 * i + 3] = v.w;
    }
  }

  // Phase C: 8 triangular matvecs; all coefficients wave-uniform (SGPR loads)
  float s2 = 0.0f;
  #pragma unroll 1                      // keep k-loop rolled: ~4.5KB body, I$-friendly
  for (int k = 0; k < NCLS; ++k) {
    const float* __restrict__ tri  = g_tri  + k * TRI;
    const float* __restrict__ offn = g_offn + k * NCH;
    float maha = 0.0f;
    int idx = 0;
    #pragma unroll
    for (int c = 0; c < NCH; ++c) {
      float z = offn[c];               // = -(Linv@mean)[c]
      #pragma unroll
      for (int m = 0; m <= c; ++m) z = fmaf(tri[idx + m], xv[m], z);
      idx += c + 1;
      maha = fmaf(z, z, maha);
    }
    // prob = exp(-0.5*maha - 16*ln(2pi) - logdet) via exp2
    const float p = exp2f(fmaf(maha, -0.72134752044448170368f, g_lc2[k]));
    gs[t * 9 + k] = p;
    s2 = fmaf(p, p, s2);
  }
  gs[t * 9 + 8] = rsqrtf(fmaxf(s2, 1e-12f));
  __syncthreads();

  // Phase D: epilogue. One pixel per wave-iteration; lane l emits elements
  // [l*4, l*4+4) of that pixel's 256-float output row -> 1KB coalesced store.
  const int lane = t & 63;
  const int w    = t >> 6;
  const int kk   = lane >> 3;          // class for this lane's chunk
  const int ch   = lane & 7;           // float4 chunk of x
  float* ob = out + (pixBase + (long long)w * 64) * (NCLS * NCH) + lane * 4;
  #pragma unroll 4
  for (int i = 0; i < 64; ++i) {
    const int p = w * 64 + i;
    const float g = gs[p * 9 + kk] * gs[p * 9 + 8];   // prob * rsqrt-norm (broadcast reads)
    const float4 xc = reinterpret_cast<const float4*>(xs)[p * 8 + (ch ^ (p & 7))];
    float4 o;
    o.x = g * xc.x; o.y = g * xc.y; o.z = g * xc.z; o.w = g * xc.w;
    *reinterpret_cast<float4*>(ob) = o;
    ob += NCLS * NCH;
  }
}

// ---------------------------------------------------------------------------
extern "C" void kernel_launch(void* const* d_in, const int* in_sizes, int n_in,
                              void* d_out, int out_size, void* d_ws, size_t ws_size,
                              hipStream_t stream) {
  const float* x     = (const float*)d_in[0];  // [8,256,256,32]
  const float* mean  = (const float*)d_in[1];  // [8,32]
  const float* scale = (const float*)d_in[2];  // [8,32,32]
  float* out = (float*)d_out;                  // [8,256,256,256]

  hipLaunchKernelGGL(setup_kernel, dim3(1), dim3(256), 0, stream, mean, scale);
  hipLaunchKernelGGL(fuzzy_main, dim3(NPIX / 256), dim3(256), 0, stream, x, out);
}